// Round 1
// baseline (149.211 us; speedup 1.0000x reference)
//
#include <hip/hip_runtime.h>
#include <math.h>
#include <complex>

// SO3 irrep rotation: out = Dy(alpha) J Dy(beta) J Dy(gamma) x, per irrep l=0..8, mul=64.
// R8: compose-once-apply-many. The 5-stage operator D_l = Dy(a) J Dy(b) J Dy(g) is
// per-ROW constant; previous kernels recomputed it implicitly in every channel lane
// (~2260 FMA/channel). Now:
//   phase 1 (per wave, cooperative): compose D_l into LDS.
//       P  = Dy(beta) * (J * Dy(gamma))   -- Dy is cross-sparse (2 nz/row), 8 FMA/elt
//       D  = Dy(alpha) * (J * P)          -- one dense 17x17x17 product, pair-fused
//     cost ~ sum d^3 + O(d^2) ~= 19k FMA / 64 lanes ~= 300 wave-insts per row.
//   phase 2 (lane = channel): dense matvec out = D*x per l-block: 969 FMA/channel
//     (vs 2260), D broadcast from LDS via ds_read_b128 (uniform addr, conflict-free,
//     rows padded to 16B so b128 works).
// Memory pattern unchanged (the part that was already right): cached dword loads
// (L3 serves ~half of x), nontemporal dword stores. J staged host->d_ws->LDS
// (kernarg dynamic indexing would scratch-copy, rule #20).

#define LMAX 8
#define BATCH 16384
#define DIM 5184
#define NJ 969   // sum (2l+1)^2
#define NP 1140  // padded D size: sum (2l+1)*rp(l)

__host__ __device__ constexpr int d_of(int l) { return 2 * l + 1; }
__host__ __device__ constexpr int joff_u(int l) {
    int o = 0;
    for (int k = 0; k < l; ++k) o += d_of(k) * d_of(k);
    return o;
}
__host__ __device__ constexpr int rp_of(int l) { return (d_of(l) + 3) & ~3; }  // row pitch, mult of 4
__host__ __device__ constexpr int poff_u(int l) {
    int o = 0;
    for (int k = 0; k < l; ++k) o += d_of(k) * rp_of(k);
    return o;
}

struct JPack { float v[NJ]; };

// ---------------- host-side J computation (validated R1-R7, unchanged) ----------------
static void compute_J_host(JPack* jp) {
    for (int l = 0; l <= LMAX; ++l) {
        const int d = 2 * l + 1;
        std::complex<double> q[289], Ac[289], T1[289];
        double A[289], E[289], Tm[289], P[289];
        const double is2 = 1.0 / std::sqrt(2.0);
        static const double pr[4] = {1.0, 0.0, -1.0, 0.0};
        static const double pim[4] = {0.0, -1.0, 0.0, 1.0};
        const int ph = l & 3;
        for (int i = 0; i < d; ++i) {
            for (int j = 0; j < d; ++j) {
                double re = 0.0, im = 0.0;
                const int mm = i - l;
                if (mm < 0) {
                    if (j == l - mm) re = is2;
                    if (j == l + mm) im = -is2;
                } else if (mm == 0) {
                    if (j == l) re = 1.0;
                } else {
                    const double sgn = (mm & 1) ? -1.0 : 1.0;
                    if (j == l + mm) re = sgn * is2;
                    if (j == l - mm) im = sgn * is2;
                }
                q[i * d + j] = std::complex<double>(re * pr[ph] - im * pim[ph],
                                                    re * pim[ph] + im * pr[ph]);
                double xr = 0.0;
                if (j == i - 1) {
                    const double m = (double)(i - 1 - l);
                    xr += -0.5 * std::sqrt((double)l * (l + 1) - m * (m + 1));
                }
                if (j == i + 1) {
                    const double m = (double)(i - l + 1);
                    xr += 0.5 * std::sqrt((double)l * (l + 1) - m * (m - 1));
                }
                Ac[i * d + j] = std::complex<double>(xr, (i == j) ? (double)(i - l) : 0.0);
            }
        }
        for (int i = 0; i < d; ++i)
            for (int j = 0; j < d; ++j) {
                std::complex<double> s = 0.0;
                for (int k = 0; k < d; ++k) s += Ac[i * d + k] * q[k * d + j];
                T1[i * d + j] = s;
            }
        for (int i = 0; i < d; ++i)
            for (int j = 0; j < d; ++j) {
                std::complex<double> s = 0.0;
                for (int k = 0; k < d; ++k) s += std::conj(q[k * d + i]) * T1[k * d + j];
                A[i * d + j] = s.real() * (M_PI / std::sqrt(2.0));
            }
        double mx = 0.0;
        for (int i = 0; i < d; ++i) {
            double s = 0.0;
            for (int k = 0; k < d; ++k) s += std::fabs(A[i * d + k]);
            mx = std::fmax(mx, s);
        }
        int sh = 0;
        while (mx > 0.25 && sh < 60) { mx *= 0.5; ++sh; }
        const double sc = std::ldexp(1.0, -sh);
        for (int t = 0; t < d * d; ++t) A[t] *= sc;
        for (int i = 0; i < d; ++i)
            for (int j = 0; j < d; ++j) E[i * d + j] = Tm[i * d + j] = (i == j) ? 1.0 : 0.0;
        for (int kk = 1; kk <= 16; ++kk) {
            for (int i = 0; i < d; ++i)
                for (int j = 0; j < d; ++j) {
                    double s = 0.0;
                    for (int k = 0; k < d; ++k) s += Tm[i * d + k] * A[k * d + j];
                    P[i * d + j] = s / (double)kk;
                }
            for (int t = 0; t < d * d; ++t) { Tm[t] = P[t]; E[t] += P[t]; }
        }
        for (int q2 = 0; q2 < sh; ++q2) {
            for (int i = 0; i < d; ++i)
                for (int j = 0; j < d; ++j) {
                    double s = 0.0;
                    for (int k = 0; k < d; ++k) s += E[i * d + k] * E[k * d + j];
                    P[i * d + j] = s;
                }
            for (int t = 0; t < d * d; ++t) E[t] = P[t];
        }
        for (int i = 0; i < d; ++i)
            for (int j = 0; j < d; ++j)
                jp->v[joff_u(l) + i * d + j] = (float)E[i * d + j];
    }
}

// ---------------- device: compose D_l into LDS ----------------
// Dy(theta)[i,j] = delta_{j,i} cos((l-i)th) + delta_{j,d-1-i} sin((l-i)th)
//   (sign convention f_i = l-i verified against the passing R7 rotY).
// Right-mult:  (A*Dy)[i,j] = A[i,j] c_{l-j} - A[i,d-1-j] s_{l-j}
// Left-mult:   (Dy*A)[i,j] = c_{l-i} A[i,j] + s_{l-i} A[d-1-i,j]
// T[a][0][m+8] = cos(m*th_a), T[a][1][m+8] = sin(m*th_a); a: 0=gamma,1=beta,2=alpha.
template <int L>
__device__ __forceinline__ void compose(const float* __restrict__ sJ,
                                        float* __restrict__ Pw,
                                        float* __restrict__ Dw,
                                        const float (&T)[3][2][17],
                                        int lane) {
    constexpr int d = d_of(L), h = (d + 1) / 2, RP = rp_of(L);
    const float* J = sJ + joff_u(L);
    float* D = Dw + poff_u(L);
    // stage A: Pw = Dy(beta) * (J * Dy(gamma)), pair rows (i, d-1-i) in one lane
    for (int t = lane; t < h * d; t += 64) {
        const int i = t / d, j = t - i * d;
        const int i2 = d - 1 - i, j2 = d - 1 - j;
        const float cg = T[0][0][(L - j) + 8], sg = T[0][1][(L - j) + 8];
        const float p1a = J[i * d + j] * cg - J[i * d + j2] * sg;      // (J*Dy(g))[i ,j]
        const float p1b = J[i2 * d + j] * cg - J[i2 * d + j2] * sg;    // (J*Dy(g))[i2,j]
        const float cb = T[1][0][(L - i) + 8], sb = T[1][1][(L - i) + 8];
        Pw[i * d + j]  = cb * p1a + sb * p1b;
        Pw[i2 * d + j] = cb * p1b - sb * p1a;   // (l-i2) = -(l-i): cos even, sin odd
    }
    __syncthreads();
    // stage B: D = Dy(alpha) * (J * Pw), dense product pair-fused (shares Pw column)
    for (int t = lane; t < h * d; t += 64) {
        const int i = t / d, j = t - i * d;
        const int i2 = d - 1 - i;
        float ta = 0.f, tb = 0.f;
#pragma unroll
        for (int k = 0; k < d; ++k) {
            const float p = Pw[k * d + j];
            ta += J[i * d + k] * p;
            tb += J[i2 * d + k] * p;
        }
        const float ca = T[2][0][(L - i) + 8], sa = T[2][1][(L - i) + 8];
        D[i * RP + j]  = ca * ta + sa * tb;
        D[i2 * RP + j] = ca * tb - sa * ta;
    }
    __syncthreads();
}

// ---------------- device: apply D_l (lane = channel) ----------------
template <int L>
__device__ __forceinline__ void apply(const float* __restrict__ xb,
                                      float* __restrict__ ob,
                                      const float* __restrict__ Dw) {
    constexpr int d = d_of(L), RP = rp_of(L);
    const float* __restrict__ D = Dw + poff_u(L);
    const float* p = xb + 64 * L * L;
    float* o = ob + 64 * L * L;
    float A[d];
#pragma unroll
    for (int i = 0; i < d; ++i) A[i] = p[i * 64];   // cached loads (L3 reuse)
#pragma unroll
    for (int i = 0; i < d; ++i) {
        const float4* row = reinterpret_cast<const float4*>(D + i * RP);  // 16B aligned
        float acc = 0.f;
#pragma unroll
        for (int q = 0; q < RP / 4; ++q) {
            const float4 f = row[q];   // uniform addr -> LDS broadcast, conflict-free
            if (4 * q + 0 < d) acc += f.x * A[4 * q + 0];
            if (4 * q + 1 < d) acc += f.y * A[4 * q + 1];
            if (4 * q + 2 < d) acc += f.z * A[4 * q + 2];
            if (4 * q + 3 < d) acc += f.w * A[4 * q + 3];
        }
        __builtin_nontemporal_store(acc, o + i * 64);
    }
}

__global__ __launch_bounds__(256) void rot_main(const float* __restrict__ gamma,
                                                const float* __restrict__ beta,
                                                const float* __restrict__ alpha,
                                                const float* __restrict__ x,
                                                float* __restrict__ out,
                                                const float* __restrict__ Jg) {
    __shared__ float sJ[NJ];
    __shared__ __align__(16) float sD[4][NP];    // composed D per wave (rows padded)
    __shared__ float sP[4][289];                 // compose scratch per wave
    __shared__ float sT[4][3][2][17];            // trig tables per wave
    // LDS total: 3876 + 18240 + 4624 + 1632 = 28372 B -> 5 blocks/CU (20 waves/CU)

    const int tid = threadIdx.x;
    const int wave = tid >> 6, lane = tid & 63;
    const int b = blockIdx.x * 4 + wave;   // one batch row per wave

    for (int i = tid; i < NJ; i += 256) sJ[i] = Jg[i];

    if (lane < 51) {   // 3 angles x 17 harmonics: cos/sin(m*theta), m in [-8,8]
        const int a = lane / 17, mm = lane - a * 17;
        const float th = (a == 0) ? gamma[b] : ((a == 1) ? beta[b] : alpha[b]);
        float s, c;
        __sincosf((float)(mm - 8) * th, &s, &c);
        sT[wave][a][0][mm] = c;
        sT[wave][a][1][mm] = s;
    }
    __syncthreads();

    const float (&T)[3][2][17] = sT[wave];
    float* Pw = sP[wave];
    float* Dw = sD[wave];

    compose<0>(sJ, Pw, Dw, T, lane);
    compose<1>(sJ, Pw, Dw, T, lane);
    compose<2>(sJ, Pw, Dw, T, lane);
    compose<3>(sJ, Pw, Dw, T, lane);
    compose<4>(sJ, Pw, Dw, T, lane);
    compose<5>(sJ, Pw, Dw, T, lane);
    compose<6>(sJ, Pw, Dw, T, lane);
    compose<7>(sJ, Pw, Dw, T, lane);
    compose<8>(sJ, Pw, Dw, T, lane);

    const float* xb = x + (size_t)b * DIM + lane;
    float* ob = out + (size_t)b * DIM + lane;

    apply<0>(xb, ob, Dw);
    apply<1>(xb, ob, Dw);
    apply<2>(xb, ob, Dw);
    apply<3>(xb, ob, Dw);
    apply<4>(xb, ob, Dw);
    apply<5>(xb, ob, Dw);
    apply<6>(xb, ob, Dw);
    apply<7>(xb, ob, Dw);
    apply<8>(xb, ob, Dw);
}

extern "C" void kernel_launch(void* const* d_in, const int* in_sizes, int n_in,
                              void* d_out, int out_size, void* d_ws, size_t ws_size,
                              hipStream_t stream) {
    const float* gamma = (const float*)d_in[0];
    const float* beta  = (const float*)d_in[1];
    const float* alpha = (const float*)d_in[2];
    const float* x     = (const float*)d_in[3];
    float* out = (float*)d_out;

    static JPack jp;
    static bool init = false;
    if (!init) { compute_J_host(&jp); init = true; }   // deterministic, pure host math

    // J -> workspace (3876 B); graph-capture-safe async copy, static host source.
    hipMemcpyAsync(d_ws, jp.v, sizeof(JPack), hipMemcpyHostToDevice, stream);

    hipLaunchKernelGGL(rot_main, dim3(BATCH / 4), dim3(256), 0, stream,
                       gamma, beta, alpha, x, out, (const float*)d_ws);
}

// Round 2
// 141.016 us; speedup vs baseline: 1.0581x; 1.0581x over previous
//
#include <hip/hip_runtime.h>
#include <math.h>
#include <complex>

// SO3 irrep rotation: out = Dy(alpha) J Dy(beta) J Dy(gamma) x, per irrep l=0..8, mul=64.
// R9 = R8 (compose-once-apply-many, math unchanged & harness-verified) minus the
// serialization that made R8 regress:
//   - NO block-wide barriers in the main loop (R8 had 18). Each wave owns its row and
//     its LDS slices; wave-internal RAW (stage A -> stage B -> apply) is enforced with
//     per-wave `s_waitcnt lgkmcnt(0)` + sched_barrier(0) (rule #18). Waves drift ->
//     VALU/LDS/HBM pipes overlap via TLP instead of running in lockstep phases.
//   - x-load burst issued BEFORE compose of the same block: HBM/L3 latency hides
//     under compose VALU.
//   - sP scratch eliminated by aliasing into dead sD regions (l=8 composed first using
//     the unwritten D[0..5] region; l=7..0 reuse the dead D[8] region). LDS
//     28.4 KB -> 23.7 KB -> 6 blocks/CU (24 waves) instead of 5.
// Memory pattern unchanged: cached dword loads (L3 serves ~half of x), NT stores.

#define LMAX 8
#define BATCH 16384
#define DIM 5184
#define NJ 969   // sum (2l+1)^2
#define NP 1140  // padded D size: sum (2l+1)*rp(l)

__host__ __device__ constexpr int d_of(int l) { return 2 * l + 1; }
__host__ __device__ constexpr int joff_u(int l) {
    int o = 0;
    for (int k = 0; k < l; ++k) o += d_of(k) * d_of(k);
    return o;
}
__host__ __device__ constexpr int rp_of(int l) { return (d_of(l) + 3) & ~3; }  // row pitch, mult of 4
__host__ __device__ constexpr int poff_u(int l) {
    int o = 0;
    for (int k = 0; k < l; ++k) o += d_of(k) * rp_of(k);
    return o;
}
// poff: 0,4,16,56,112,220,352,560,800 ; NP=1140.
// Compose scratch aliasing (per wave, within sD[wave]):
//   L=8: Pw = Dw+0   (covers D[0..5] regions [0,352) -- not yet written; D[8] at [800,1140))
//   L<8: Pw = Dw+800 (dead D[8] region, 340 >= 289 floats; D[l] regions are < 560)

struct JPack { float v[NJ]; };

// ---------------- host-side J computation (validated R1-R8, unchanged) ----------------
static void compute_J_host(JPack* jp) {
    for (int l = 0; l <= LMAX; ++l) {
        const int d = 2 * l + 1;
        std::complex<double> q[289], Ac[289], T1[289];
        double A[289], E[289], Tm[289], P[289];
        const double is2 = 1.0 / std::sqrt(2.0);
        static const double pr[4] = {1.0, 0.0, -1.0, 0.0};
        static const double pim[4] = {0.0, -1.0, 0.0, 1.0};
        const int ph = l & 3;
        for (int i = 0; i < d; ++i) {
            for (int j = 0; j < d; ++j) {
                double re = 0.0, im = 0.0;
                const int mm = i - l;
                if (mm < 0) {
                    if (j == l - mm) re = is2;
                    if (j == l + mm) im = -is2;
                } else if (mm == 0) {
                    if (j == l) re = 1.0;
                } else {
                    const double sgn = (mm & 1) ? -1.0 : 1.0;
                    if (j == l + mm) re = sgn * is2;
                    if (j == l - mm) im = sgn * is2;
                }
                q[i * d + j] = std::complex<double>(re * pr[ph] - im * pim[ph],
                                                    re * pim[ph] + im * pr[ph]);
                double xr = 0.0;
                if (j == i - 1) {
                    const double m = (double)(i - 1 - l);
                    xr += -0.5 * std::sqrt((double)l * (l + 1) - m * (m + 1));
                }
                if (j == i + 1) {
                    const double m = (double)(i - l + 1);
                    xr += 0.5 * std::sqrt((double)l * (l + 1) - m * (m - 1));
                }
                Ac[i * d + j] = std::complex<double>(xr, (i == j) ? (double)(i - l) : 0.0);
            }
        }
        for (int i = 0; i < d; ++i)
            for (int j = 0; j < d; ++j) {
                std::complex<double> s = 0.0;
                for (int k = 0; k < d; ++k) s += Ac[i * d + k] * q[k * d + j];
                T1[i * d + j] = s;
            }
        for (int i = 0; i < d; ++i)
            for (int j = 0; j < d; ++j) {
                std::complex<double> s = 0.0;
                for (int k = 0; k < d; ++k) s += std::conj(q[k * d + i]) * T1[k * d + j];
                A[i * d + j] = s.real() * (M_PI / std::sqrt(2.0));
            }
        double mx = 0.0;
        for (int i = 0; i < d; ++i) {
            double s = 0.0;
            for (int k = 0; k < d; ++k) s += std::fabs(A[i * d + k]);
            mx = std::fmax(mx, s);
        }
        int sh = 0;
        while (mx > 0.25 && sh < 60) { mx *= 0.5; ++sh; }
        const double sc = std::ldexp(1.0, -sh);
        for (int t = 0; t < d * d; ++t) A[t] *= sc;
        for (int i = 0; i < d; ++i)
            for (int j = 0; j < d; ++j) E[i * d + j] = Tm[i * d + j] = (i == j) ? 1.0 : 0.0;
        for (int kk = 1; kk <= 16; ++kk) {
            for (int i = 0; i < d; ++i)
                for (int j = 0; j < d; ++j) {
                    double s = 0.0;
                    for (int k = 0; k < d; ++k) s += Tm[i * d + k] * A[k * d + j];
                    P[i * d + j] = s / (double)kk;
                }
            for (int t = 0; t < d * d; ++t) { Tm[t] = P[t]; E[t] += P[t]; }
        }
        for (int q2 = 0; q2 < sh; ++q2) {
            for (int i = 0; i < d; ++i)
                for (int j = 0; j < d; ++j) {
                    double s = 0.0;
                    for (int k = 0; k < d; ++k) s += E[i * d + k] * E[k * d + j];
                    P[i * d + j] = s;
                }
            for (int t = 0; t < d * d; ++t) E[t] = P[t];
        }
        for (int i = 0; i < d; ++i)
            for (int j = 0; j < d; ++j)
                jp->v[joff_u(l) + i * d + j] = (float)E[i * d + j];
    }
}

// per-wave LDS RAW fence: drain this wave's outstanding LDS ops, pin program order.
__device__ __forceinline__ void wave_lds_fence() {
    asm volatile("s_waitcnt lgkmcnt(0)" ::: "memory");
    __builtin_amdgcn_sched_barrier(0);
}

// ---------------- per-l block: load burst -> compose (2 stages) -> matvec -> store ----
// Dy(theta)[i,j] = delta_{j,i} cos((l-i)th) + delta_{j,d-1-i} sin((l-i)th)
// T[a][0][m+8] = cos(m*th_a), T[a][1][m+8] = sin(m*th_a); a: 0=gamma,1=beta,2=alpha.
// Math identical to R8 (harness-verified, absmax 0.0156).
template <int L, int PWOFF>
__device__ __forceinline__ void process(const float* __restrict__ xb,
                                        float* __restrict__ ob,
                                        const float* __restrict__ sJ,
                                        float* Dw,
                                        const float (&T)[3][2][17],
                                        int lane) {
    constexpr int d = d_of(L), h = (d + 1) / 2, RP = rp_of(L);
    const float* J = sJ + joff_u(L);
    float* D = Dw + poff_u(L);
    float* Pw = Dw + PWOFF;
    const float* p = xb + 64 * L * L;
    float* o = ob + 64 * L * L;

    // issue x loads first: latency hides under compose
    float A[d];
#pragma unroll
    for (int i = 0; i < d; ++i) A[i] = p[i * 64];

    // stage A: Pw = Dy(beta) * (J * Dy(gamma)), rows paired (i, d-1-i)
    for (int t = lane; t < h * d; t += 64) {
        const int i = t / d, j = t - i * d;
        const int i2 = d - 1 - i, j2 = d - 1 - j;
        const float cg = T[0][0][(L - j) + 8], sg = T[0][1][(L - j) + 8];
        const float p1a = J[i * d + j] * cg - J[i * d + j2] * sg;
        const float p1b = J[i2 * d + j] * cg - J[i2 * d + j2] * sg;
        const float cb = T[1][0][(L - i) + 8], sb = T[1][1][(L - i) + 8];
        Pw[i * d + j]  = cb * p1a + sb * p1b;
        Pw[i2 * d + j] = cb * p1b - sb * p1a;
    }
    wave_lds_fence();

    // stage B: D = Dy(alpha) * (J * Pw), pair-fused dense product
    for (int t = lane; t < h * d; t += 64) {
        const int i = t / d, j = t - i * d;
        const int i2 = d - 1 - i;
        float ta = 0.f, tb = 0.f;
#pragma unroll
        for (int k = 0; k < d; ++k) {
            const float pv = Pw[k * d + j];
            ta += J[i * d + k] * pv;
            tb += J[i2 * d + k] * pv;
        }
        const float ca = T[2][0][(L - i) + 8], sa = T[2][1][(L - i) + 8];
        D[i * RP + j]  = ca * ta + sa * tb;
        D[i2 * RP + j] = ca * tb - sa * ta;
    }
    wave_lds_fence();

    // apply: out = D * x, D broadcast from LDS (uniform addr, conflict-free b128)
#pragma unroll
    for (int i = 0; i < d; ++i) {
        const float4* row = reinterpret_cast<const float4*>(D + i * RP);  // 16B aligned
        float acc = 0.f;
#pragma unroll
        for (int q = 0; q < RP / 4; ++q) {
            const float4 f = row[q];
            if (4 * q + 0 < d) acc += f.x * A[4 * q + 0];
            if (4 * q + 1 < d) acc += f.y * A[4 * q + 1];
            if (4 * q + 2 < d) acc += f.z * A[4 * q + 2];
            if (4 * q + 3 < d) acc += f.w * A[4 * q + 3];
        }
        __builtin_nontemporal_store(acc, o + i * 64);
    }
}

__global__ __launch_bounds__(256) void rot_main(const float* __restrict__ gamma,
                                                const float* __restrict__ beta,
                                                const float* __restrict__ alpha,
                                                const float* __restrict__ x,
                                                float* __restrict__ out,
                                                const float* __restrict__ Jg) {
    __shared__ float sJ[NJ];
    __shared__ __align__(16) float sD[4][NP];    // composed D per wave; also compose scratch
    __shared__ float sT[4][3][2][17];            // trig tables per wave
    // LDS: 3876 + 18240 + 1632 = 23748 B -> 6 blocks/CU (24 waves/CU)

    const int tid = threadIdx.x;
    const int wave = tid >> 6, lane = tid & 63;
    const int b = blockIdx.x * 4 + wave;   // one batch row per wave

    for (int i = tid; i < NJ; i += 256) sJ[i] = Jg[i];

    if (lane < 51) {   // 3 angles x 17 harmonics: cos/sin(m*theta), m in [-8,8]
        const int a = lane / 17, mm = lane - a * 17;
        const float th = (a == 0) ? gamma[b] : ((a == 1) ? beta[b] : alpha[b]);
        float s, c;
        __sincosf((float)(mm - 8) * th, &s, &c);
        sT[wave][a][0][mm] = c;
        sT[wave][a][1][mm] = s;
    }
    __syncthreads();   // the ONLY block barrier: sJ (block-coop) + sT visible

    const float (&T)[3][2][17] = sT[wave];
    float* Dw = sD[wave];

    const float* xb = x + (size_t)b * DIM + lane;
    float* ob = out + (size_t)b * DIM + lane;

    // l=8 first: compose scratch aliases the not-yet-written D[0..5] region [0,352).
    // l=7..0: scratch aliases the dead D[8] region [800,1140).
    process<8, 0>(xb, ob, sJ, Dw, T, lane);
    process<7, 800>(xb, ob, sJ, Dw, T, lane);
    process<6, 800>(xb, ob, sJ, Dw, T, lane);
    process<5, 800>(xb, ob, sJ, Dw, T, lane);
    process<4, 800>(xb, ob, sJ, Dw, T, lane);
    process<3, 800>(xb, ob, sJ, Dw, T, lane);
    process<2, 800>(xb, ob, sJ, Dw, T, lane);
    process<1, 800>(xb, ob, sJ, Dw, T, lane);
    process<0, 800>(xb, ob, sJ, Dw, T, lane);
}

extern "C" void kernel_launch(void* const* d_in, const int* in_sizes, int n_in,
                              void* d_out, int out_size, void* d_ws, size_t ws_size,
                              hipStream_t stream) {
    const float* gamma = (const float*)d_in[0];
    const float* beta  = (const float*)d_in[1];
    const float* alpha = (const float*)d_in[2];
    const float* x     = (const float*)d_in[3];
    float* out = (float*)d_out;

    static JPack jp;
    static bool init = false;
    if (!init) { compute_J_host(&jp); init = true; }   // deterministic, pure host math

    // J -> workspace (3876 B); graph-capture-safe async copy, static host source.
    hipMemcpyAsync(d_ws, jp.v, sizeof(JPack), hipMemcpyHostToDevice, stream);

    hipLaunchKernelGGL(rot_main, dim3(BATCH / 4), dim3(256), 0, stream,
                       gamma, beta, alpha, x, out, (const float*)d_ws);
}